// Round 9
// baseline (1094.351 us; speedup 1.0000x reference)
//
#include <hip/hip_runtime.h>
#include <hip/hip_bf16.h>
#include <math.h>

// B=8, S=1024, D=768, H=12, DH=64, L=3, I=3072, W1S=128, nc=8, MLP=512, NCLS=3

typedef __attribute__((ext_vector_type(8))) short short8;   // 8 bf16 (4 VGPRs)
typedef __attribute__((ext_vector_type(4))) short short4v;  // 4 bf16 (8 B)
typedef __attribute__((ext_vector_type(4))) float floatx4;  // MFMA C/D

// Exact-accuracy gelu via A&S 7.1.26 rational erf (|err|<=1.5e-7).
__device__ __forceinline__ float gelu_exact(float x) {
    float ax = fabsf(x) * 0.70710678118654752440f;
    float t  = 1.f / (1.f + 0.3275911f * ax);
    float y  = t * (0.254829592f + t * (-0.284496736f + t * (1.421413741f +
               t * (-1.453152027f + t * 1.061405429f))));
    float erfv = copysignf(1.f - y * __expf(-ax * ax), x);
    return 0.5f * x * (1.f + erfv);
}

__device__ __forceinline__ short bfs(float x) {
    __hip_bfloat16 h = __float2bfloat16(x);
    short s;
    __builtin_memcpy(&s, &h, 2);
    return s;
}

__device__ __forceinline__ float bf2f(short s) {
    unsigned u = ((unsigned)(unsigned short)s) << 16;
    float f;
    __builtin_memcpy(&f, &u, 4);
    return f;
}

#define GLOAD_LDS16(g, l) __builtin_amdgcn_global_load_lds( \
    (const __attribute__((address_space(1))) void*)(g),     \
    (__attribute__((address_space(3))) void*)(l), 16, 0, 0)

// ---------------------------------------------------------------------------
// Weight convert+transpose: W[K,N] fp32 -> Wt[N,K] bf16. blockIdx.z = layer.
// ---------------------------------------------------------------------------
__global__ __launch_bounds__(256) void transpose_bf16(
    const float* __restrict__ W, __hip_bfloat16* __restrict__ Wt,
    int K, int N, long inLS, long outLS)
{
    __shared__ float tile[32][33];
    int l = blockIdx.z;
    const float* Wl = W + (long)l * inLS;
    __hip_bfloat16* Wtl = Wt + (long)l * outLS;
    int lx = threadIdx.x & 31, ly = threadIdx.x >> 5;
    int kb = blockIdx.y * 32, nb = blockIdx.x * 32;
    #pragma unroll
    for (int r = 0; r < 32; r += 8)
        tile[ly + r][lx] = Wl[(long)(kb + ly + r) * N + nb + lx];
    __syncthreads();
    #pragma unroll
    for (int r = 0; r < 32; r += 8)
        Wtl[(long)(nb + ly + r) * K + kb + lx] = __float2bfloat16(tile[lx][ly + r]);
}

__global__ void pack_qkv_bias(const float* __restrict__ bq,
                              const float* __restrict__ bk,
                              const float* __restrict__ bv,
                              float* __restrict__ out)
{
    int l = blockIdx.x, tid = threadIdx.x;   // 768 threads
    out[l * 2304 + tid]        = bq[l * 768 + tid];
    out[l * 2304 + 768 + tid]  = bk[l * 768 + tid];
    out[l * 2304 + 1536 + tid] = bv[l * 768 + tid];
}

// ---------------------------------------------------------------------------
// Patchify gather: x (8,3,64,32,32) fp32 -> xr_bf [8192 tokens][192] bf16.
// ---------------------------------------------------------------------------
__global__ __launch_bounds__(192) void gather_x(
    const float* __restrict__ x, __hip_bfloat16* __restrict__ xr)
{
    int tok = blockIdx.x;           // 0..8191
    int b = tok >> 10, s = tok & 1023;
    int tci = s >> 6, sci = (s >> 3) & 7, scj = s & 7;
    int f = threadIdx.x;            // 0..191
    int ch  = f % 3;
    int crc = f / 3;
    int cr1 = crc >> 4, cr2 = (crc >> 2) & 3, cr3 = crc & 3;
    float v = x[(((b * 3 + ch) * 64) + cr1 * 16 + tci) * 1024 +
                (cr2 * 8 + sci) * 32 + cr3 * 8 + scj];
    xr[(long)tok * 192 + f] = __float2bfloat16(v);
}

// ---------------------------------------------------------------------------
// bf16 MFMA GEMM: C[M,N](bf16) = A[M,K](bf16) @ Bt[N,K](bf16)^T + bias.
// 128x128 tile, BK=32, 4 waves. RING-4 LDS + BARRIER EVERY 2 ITERS:
// __syncthreads drains vmcnt(0), so pipeline distance == compute phases
// between barriers. Pairing iters gives loads 2 compute phases (~800-1000
// cyc) to cover the ~600-900 cyc latency -> drain ~free (R8 dbuf only gave
// 1 phase -> ~300 cyc residual stall every iter, MfmaUtil stuck ~20%).
// All K here are multiples of 64 (192/768/3072) so the pair loop is exact.
// 1-D grid, by = L & 63; XOR-swizzled LDS; LDS-transpose epilogue.
// ---------------------------------------------------------------------------
template<int ACT>
__global__ __launch_bounds__(256) void mfma_gemm(
    const __hip_bfloat16* __restrict__ A, const __hip_bfloat16* __restrict__ Bt,
    const float* __restrict__ bias, __hip_bfloat16* __restrict__ C,
    int M, int N, int K)
{
    __shared__ short lds_raw[32768];           // As[4][4096] | Bs[4][4096] = 64 KB
    __hip_bfloat16* As = (__hip_bfloat16*)lds_raw;
    __hip_bfloat16* Bs = As + 16384;
    int tid  = threadIdx.x;
    int wave = tid >> 6, lane = tid & 63;
    int L = blockIdx.x;
    long m0 = (long)(L & 63) * 128, n0 = (long)(L >> 6) * 128;
    int wr = wave >> 1, wc = wave & 1;
    floatx4 acc[4][4] = {};

    int srow = (wave * 128 + lane) >> 2;
    int sch  = (lane & 3) ^ ((lane >> 3) & 3);      // source-side XOR swizzle
    const __hip_bfloat16* Ag = A  + (m0 + srow) * K + sch * 8;
    const __hip_bfloat16* Bg = Bt + (n0 + srow) * K + sch * 8;
    int lm = lane & 15, lg = lane >> 4;
    int lk8 = ((lg ^ ((lm >> 1) & 3))) * 8;         // read-side swizzle

    auto stage = [&](int buf, int k0) {
        __hip_bfloat16* a = As + buf * 4096 + wave * 1024;
        __hip_bfloat16* b = Bs + buf * 4096 + wave * 1024;
        GLOAD_LDS16(Ag + k0,          a);
        GLOAD_LDS16(Ag + 16 * K + k0, a + 512);
        GLOAD_LDS16(Bg + k0,          b);
        GLOAD_LDS16(Bg + 16 * K + k0, b + 512);
    };
    auto compute = [&](int buf) {
        const __hip_bfloat16* Ab = As + buf * 4096;
        const __hip_bfloat16* Bb = Bs + buf * 4096;
        short8 af[4], bf4[4];
        #pragma unroll
        for (int mi = 0; mi < 4; mi++)
            af[mi] = *(const short8*)&Ab[(wr * 64 + mi * 16 + lm) * 32 + lk8];
        #pragma unroll
        for (int ni = 0; ni < 4; ni++)
            bf4[ni] = *(const short8*)&Bb[(wc * 64 + ni * 16 + lm) * 32 + lk8];
        #pragma unroll
        for (int mi = 0; mi < 4; mi++)
            #pragma unroll
            for (int ni = 0; ni < 4; ni++)
                acc[mi][ni] = __builtin_amdgcn_mfma_f32_16x16x32_bf16(
                    af[mi], bf4[ni], acc[mi][ni], 0, 0, 0);
    };

    stage(0, 0);
    stage(1, 32);
    int nIter = K >> 5;                  // even for all K used here
    for (int i = 0; i < nIter; i += 2) {
        __syncthreads();                 // drains loads issued LAST pair (2 phases old)
        int k2 = (i + 2) << 5;
        if (k2 < K) {
            stage((i + 2) & 3, k2);
            stage((i + 3) & 3, k2 + 32);
        }
        compute(i & 3);
        compute((i + 1) & 3);
    }
    __syncthreads();

    // ---- epilogue: bias(+gelu), LDS transpose, coalesced bf16 stores ----
    float bvv[4];
    #pragma unroll
    for (int ni = 0; ni < 4; ni++)
        bvv[ni] = bias[n0 + wc * 64 + ni * 16 + lm];
    int erow = tid >> 4;            // 0..15
    int ecol = (tid & 15) * 8;      // 0..120
    #pragma unroll
    for (int p = 0; p < 2; p++) {
        if (wr == p) {
            #pragma unroll
            for (int mi = 0; mi < 4; mi++)
                #pragma unroll
                for (int ni = 0; ni < 4; ni++)
                    #pragma unroll
                    for (int j = 0; j < 4; j++) {
                        float o = acc[mi][ni][j] + bvv[ni];
                        if (ACT == 1) o = gelu_exact(o);
                        lds_raw[(mi * 16 + lg * 4 + j) * 136 +
                                wc * 64 + ni * 16 + lm] = bfs(o);
                    }
        }
        __syncthreads();
        #pragma unroll
        for (int rr = 0; rr < 4; rr++) {
            int r = erow + rr * 16;
            short8 v = *(const short8*)&lds_raw[r * 136 + ecol];
            *(short8*)&C[(m0 + p * 64 + r) * N + n0 + ecol] = v;
        }
        __syncthreads();
    }
}

// ---------------------------------------------------------------------------
// h = LayerNorm(t_bf + pos_emb[s] + tok_emb); fp32 h + bf16 mirror.
// ---------------------------------------------------------------------------
__global__ __launch_bounds__(192) void pos_ln_kernel(
    const __hip_bfloat16* __restrict__ t, const float* __restrict__ pos_emb,
    const float* __restrict__ tok_emb, const float* __restrict__ ln_s,
    const float* __restrict__ ln_b, float* __restrict__ h,
    __hip_bfloat16* __restrict__ hbf)
{
    int tok = blockIdx.x;
    int s = tok & 1023;
    int tid = threadIdx.x;        // 0..191
    int d = tid * 4;
    __shared__ float red[6];
    short4v tv = *(const short4v*)&t[(long)tok * 768 + d];
    float4 pv = *(const float4*)&pos_emb[s * 768 + d];
    float4 kv = *(const float4*)&tok_emb[d];
    float a[4] = { bf2f(tv[0]) + pv.x + kv.x, bf2f(tv[1]) + pv.y + kv.y,
                   bf2f(tv[2]) + pv.z + kv.z, bf2f(tv[3]) + pv.w + kv.w };
    float sum = a[0] + a[1] + a[2] + a[3];
    float sumsq = a[0]*a[0] + a[1]*a[1] + a[2]*a[2] + a[3]*a[3];
    #pragma unroll
    for (int off = 32; off; off >>= 1) {
        sum   += __shfl_down(sum, off, 64);
        sumsq += __shfl_down(sumsq, off, 64);
    }
    if ((tid & 63) == 0) { red[tid >> 6] = sum; red[3 + (tid >> 6)] = sumsq; }
    __syncthreads();
    sum   = red[0] + red[1] + red[2];
    sumsq = red[3] + red[4] + red[5];
    float mean = sum * (1.f / 768.f);
    float var  = sumsq * (1.f / 768.f) - mean * mean;
    float rs   = rsqrtf(var + 1e-12f);
    float4 sv = *(const float4*)&ln_s[d];
    float4 bv = *(const float4*)&ln_b[d];
    float4 o;
    o.x = (a[0] - mean) * rs * sv.x + bv.x;
    o.y = (a[1] - mean) * rs * sv.y + bv.y;
    o.z = (a[2] - mean) * rs * sv.z + bv.z;
    o.w = (a[3] - mean) * rs * sv.w + bv.w;
    *(float4*)&h[(long)tok * 768 + d] = o;
    short4v ob = { bfs(o.x), bfs(o.y), bfs(o.z), bfs(o.w) };
    *(short4v*)&hbf[(long)tok * 768 + d] = ob;
}

// ---------------------------------------------------------------------------
// MFMA band attention; QKV is bf16 [8192, 2304] (q|k|v packed per token).
// ---------------------------------------------------------------------------
__global__ __launch_bounds__(256) void attn_kernel(
    const __hip_bfloat16* __restrict__ QKV, __hip_bfloat16* __restrict__ Ob)
{
    __shared__ __hip_bfloat16 KV[128 * 72];       // Ks[128][72]  /  Vt[64][136]
    __shared__ __hip_bfloat16 Pl[4][32 * 136];    // per-wave P[query][key]
    __shared__ float alpha_s[4][32];
    __shared__ float l_s[4][32];

    int blk = blockIdx.x;
    int ci = blk & 7, hh = (blk >> 3) % 12, b = blk / 96;
    int tid = threadIdx.x, w = tid >> 6, lane = tid & 63;
    int lm = lane & 15, lg = lane >> 4;
    __hip_bfloat16* Pw = &Pl[w][0];

    short8 qf[2][2];
    #pragma unroll
    for (int nt = 0; nt < 2; nt++) {
        int q = ci * 128 + w * 32 + nt * 16 + lm;
        const __hip_bfloat16* qp = &QKV[((long)(b * 1024 + q)) * 2304 + hh * 64];
        #pragma unroll
        for (int ks = 0; ks < 2; ks++)
            qf[nt][ks] = *(const short8*)(qp + ks * 32 + lg * 8);
    }

    floatx4 accO[2][4] = {};
    float m_run[2] = {-1e30f, -1e30f};
    float l_run[2] = {0.f, 0.f};

    for (int tt = 0; tt < 3; tt++) {
        __syncthreads();
        #pragma unroll
        for (int i = 0; i < 4; i++) {
            int e = tid + i * 256;          // 0..1023
            int jj = e >> 3, dd = (e & 7) * 8;
            int kpos = ci * 128 + tt * 128 + jj - 128;
            short8 kv = {};
            if (kpos >= 0 && kpos < 1024)
                kv = *(const short8*)&QKV[((long)(b * 1024 + kpos)) * 2304 + 768 + hh * 64 + dd];
            *(short8*)&KV[jj * 72 + dd] = kv;
        }
        __syncthreads();

        floatx4 accS[8][2] = {};
        #pragma unroll
        for (int ks = 0; ks < 2; ks++)
            #pragma unroll
            for (int mt = 0; mt < 8; mt++) {
                short8 kf = *(const short8*)&KV[(mt * 16 + lm) * 72 + ks * 32 + lg * 8];
                accS[mt][0] = __builtin_amdgcn_mfma_f32_16x16x32_bf16(kf, qf[0][ks], accS[mt][0], 0, 0, 0);
                accS[mt][1] = __builtin_amdgcn_mfma_f32_16x16x32_bf16(kf, qf[1][ks], accS[mt][1], 0, 0, 0);
            }

        float tmax[2] = {-1e30f, -1e30f};
        #pragma unroll
        for (int nt = 0; nt < 2; nt++) {
            int r = w * 32 + nt * 16 + lm;
            #pragma unroll
            for (int mt = 0; mt < 8; mt++)
                #pragma unroll
                for (int j = 0; j < 4; j++) {
                    int jrel = tt * 128 + mt * 16 + lg * 4 + j;
                    int kpos = ci * 128 + jrel - 128;
                    bool valid = (jrel >= r) && (jrel <= r + 256) &&
                                 (kpos >= 0) && (kpos < 1024);
                    float s = valid ? accS[mt][nt][j] * 0.125f : -1e9f;
                    accS[mt][nt][j] = s;
                    tmax[nt] = fmaxf(tmax[nt], s);
                }
            tmax[nt] = fmaxf(tmax[nt], __shfl_xor(tmax[nt], 16));
            tmax[nt] = fmaxf(tmax[nt], __shfl_xor(tmax[nt], 32));
        }

        float al[2];
        #pragma unroll
        for (int nt = 0; nt < 2; nt++) {
            float mnew = fmaxf(m_run[nt], tmax[nt]);
            al[nt] = __expf(m_run[nt] - mnew);
            m_run[nt] = mnew;
            float ts = 0.f;
            #pragma unroll
            for (int mt = 0; mt < 8; mt++) {
                short4v pp;
                #pragma unroll
                for (int j = 0; j < 4; j++) {
                    float p = __expf(accS[mt][nt][j] - mnew);
                    ts += p;
                    pp[j] = bfs(p);
                }
                *(short4v*)&Pw[(nt * 16 + lm) * 136 + mt * 16 + lg * 4] = pp;
            }
            ts += __shfl_xor(ts, 16);
            ts += __shfl_xor(ts, 32);
            l_run[nt] = l_run[nt] * al[nt] + ts;
        }
        if (lg < 2) alpha_s[w][lg * 16 + lm] = al[lg];

        __syncthreads();
        #pragma unroll
        for (int i = 0; i < 4; i++) {
            int e = tid + i * 256;          // 0..1023
            int jj = e >> 3, dd = (e & 7) * 8;
            int kpos = ci * 128 + tt * 128 + jj - 128;
            short8 vv = {};
            if (kpos >= 0 && kpos < 1024)
                vv = *(const short8*)&QKV[((long)(b * 1024 + kpos)) * 2304 + 1536 + hh * 64 + dd];
            short* kvs = (short*)KV;
            #pragma unroll
            for (int m2 = 0; m2 < 8; m2++)
                kvs[(dd + m2) * 136 + jj] = vv[m2];
        }
        __syncthreads();

        #pragma unroll
        for (int mo = 0; mo < 2; mo++)
            #pragma unroll
            for (int j = 0; j < 4; j++) {
                float a = alpha_s[w][mo * 16 + lg * 4 + j];
                #pragma unroll
                for (int nd = 0; nd < 4; nd++)
                    accO[mo][nd][j] *= a;
            }

        #pragma unroll
        for (int kk = 0; kk < 4; kk++) {
            short8 pf[2], vf[4];
            #pragma unroll
            for (int mo = 0; mo < 2; mo++)
                pf[mo] = *(const short8*)&Pw[(mo * 16 + lm) * 136 + kk * 32 + lg * 8];
            #pragma unroll
            for (int nd = 0; nd < 4; nd++)
                vf[nd] = *(const short8*)&KV[(nd * 16 + lm) * 136 + kk * 32 + lg * 8];
            #pragma unroll
            for (int mo = 0; mo < 2; mo++)
                #pragma unroll
                for (int nd = 0; nd < 4; nd++)
                    accO[mo][nd] = __builtin_amdgcn_mfma_f32_16x16x32_bf16(
                        pf[mo], vf[nd], accO[mo][nd], 0, 0, 0);
        }
    }

    if (lg < 2) l_s[w][lg * 16 + lm] = l_run[lg];
    #pragma unroll
    for (int mo = 0; mo < 2; mo++)
        #pragma unroll
        for (int j = 0; j < 4; j++) {
            int qr = mo * 16 + lg * 4 + j;       // within-wave row, 0..31
            float rl = 1.f / l_s[w][qr];
            int q  = w * 32 + qr;
            long base = ((long)(b * 1024 + ci * 128 + q)) * 768 + hh * 64;
            #pragma unroll
            for (int nd = 0; nd < 4; nd++)
                Ob[base + nd * 16 + lm] = __float2bfloat16(accO[mo][nd][j] * rl);
        }
}

// ---------------------------------------------------------------------------
// h = LayerNorm(h + t_bf) in place; bf16 mirror. 192 thr, 16-B vector access.
// ---------------------------------------------------------------------------
__global__ __launch_bounds__(192) void add_ln_kernel(
    float* __restrict__ h, const __hip_bfloat16* __restrict__ t,
    const float* __restrict__ ln_s, const float* __restrict__ ln_b,
    __hip_bfloat16* __restrict__ hbf)
{
    int tok = blockIdx.x;
    int tid = threadIdx.x;        // 0..191
    int d = tid * 4;
    __shared__ float red[6];
    float* hrow = &h[(long)tok * 768];
    float4 hv = *(const float4*)&hrow[d];
    short4v tv = *(const short4v*)&t[(long)tok * 768 + d];
    float a[4] = { hv.x + bf2f(tv[0]), hv.y + bf2f(tv[1]),
                   hv.z + bf2f(tv[2]), hv.w + bf2f(tv[3]) };
    float sum = a[0] + a[1] + a[2] + a[3];
    float sumsq = a[0]*a[0] + a[1]*a[1] + a[2]*a[2] + a[3]*a[3];
    #pragma unroll
    for (int off = 32; off; off >>= 1) {
        sum   += __shfl_down(sum, off, 64);
        sumsq += __shfl_down(sumsq, off, 64);
    }
    if ((tid & 63) == 0) { red[tid >> 6] = sum; red[3 + (tid >> 6)] = sumsq; }
    __syncthreads();
    sum   = red[0] + red[1] + red[2];
    sumsq = red[3] + red[4] + red[5];
    float mean = sum * (1.f / 768.f);
    float var  = sumsq * (1.f / 768.f) - mean * mean;
    float rs   = rsqrtf(var + 1e-12f);
    float4 sv = *(const float4*)&ln_s[d];
    float4 bv = *(const float4*)&ln_b[d];
    float4 o;
    o.x = (a[0] - mean) * rs * sv.x + bv.x;
    o.y = (a[1] - mean) * rs * sv.y + bv.y;
    o.z = (a[2] - mean) * rs * sv.z + bv.z;
    o.w = (a[3] - mean) * rs * sv.w + bv.w;
    *(float4*)&hrow[d] = o;
    short4v ob = { bfs(o.x), bfs(o.y), bfs(o.z), bfs(o.w) };
    *(short4v*)&hbf[(long)tok * 768 + d] = ob;
}

// ---------------------------------------------------------------------------
// Head stage 1: pooled[b,d] = tanh(h_bf[b,0,:] . pool_wt[d,:] + pool_b[d]).
// ---------------------------------------------------------------------------
__global__ __launch_bounds__(256) void pool_split(
    const __hip_bfloat16* __restrict__ hbf, const __hip_bfloat16* __restrict__ pool_wt,
    const float* __restrict__ pool_b, float* __restrict__ pooled)
{
    int g = blockIdx.x * 256 + threadIdx.x;
    int out = g >> 3, t8 = g & 7;
    int b = out / 768, d = out - b * 768;
    const __hip_bfloat16* hr = hbf + (long)b * 1024 * 768;   // token 0 of batch b
    const __hip_bfloat16* wr = pool_wt + (long)d * 768;
    float acc = 0.f;
    #pragma unroll
    for (int kk = 0; kk < 96; kk += 8) {
        int k = t8 * 96 + kk;
        short8 hv = *(const short8*)&hr[k];
        short8 wv = *(const short8*)&wr[k];
        #pragma unroll
        for (int j = 0; j < 8; j++) acc += bf2f(hv[j]) * bf2f(wv[j]);
    }
    acc += __shfl_down(acc, 4, 64);
    acc += __shfl_down(acc, 2, 64);
    acc += __shfl_down(acc, 1, 64);
    if (t8 == 0) pooled[out] = tanhf(acc + pool_b[d]);
}

// ---------------------------------------------------------------------------
// Head stage 2: z_bf[b] = bf16(LN(pooled[b])). 8 blocks x 256 thr.
// ---------------------------------------------------------------------------
__global__ __launch_bounds__(256) void ln_z_kernel(
    const float* __restrict__ pooled, const float* __restrict__ hln_s,
    const float* __restrict__ hln_b, __hip_bfloat16* __restrict__ zbf)
{
    int b = blockIdx.x, tid = threadIdx.x;
    __shared__ float red[8];
    const float* pr = &pooled[b * 768];
    float p0 = pr[tid], p1 = pr[tid + 256], p2 = pr[tid + 512];
    float sum = p0 + p1 + p2;
    float sumsq = p0 * p0 + p1 * p1 + p2 * p2;
    #pragma unroll
    for (int off = 32; off; off >>= 1) {
        sum   += __shfl_down(sum, off, 64);
        sumsq += __shfl_down(sumsq, off, 64);
    }
    if ((tid & 63) == 0) { red[tid >> 6] = sum; red[4 + (tid >> 6)] = sumsq; }
    __syncthreads();
    sum   = red[0] + red[1] + red[2] + red[3];
    sumsq = red[4] + red[5] + red[6] + red[7];
    float mean = sum * (1.f / 768.f);
    float var  = sumsq * (1.f / 768.f) - mean * mean;
    float rs   = rsqrtf(var + 1e-12f);
    zbf[b * 768 + tid]       = __float2bfloat16((p0 - mean) * rs * hln_s[tid]       + hln_b[tid]);
    zbf[b * 768 + tid + 256] = __float2bfloat16((p1 - mean) * rs * hln_s[tid + 256] + hln_b[tid + 256]);
    zbf[b * 768 + tid + 512] = __float2bfloat16((p2 - mean) * rs * hln_s[tid + 512] + hln_b[tid + 512]);
}

// ---------------------------------------------------------------------------
// Head stage 3: z1[b,d] = gelu(z_bf[b] . w1t[d,:] + b1[d]).
// ---------------------------------------------------------------------------
__global__ __launch_bounds__(256) void mlp_split(
    const __hip_bfloat16* __restrict__ zbf, const __hip_bfloat16* __restrict__ w1t,
    const float* __restrict__ b1, float* __restrict__ z1)
{
    int g = blockIdx.x * 256 + threadIdx.x;
    int out = g >> 3, t8 = g & 7;
    int b = out >> 9, d = out & 511;
    const __hip_bfloat16* zr = zbf + b * 768;
    const __hip_bfloat16* wr = w1t + (long)d * 768;
    float acc = 0.f;
    #pragma unroll
    for (int kk = 0; kk < 96; kk += 8) {
        int k = t8 * 96 + kk;
        short8 zv = *(const short8*)&zr[k];
        short8 wv = *(const short8*)&wr[k];
        #pragma unroll
        for (int j = 0; j < 8; j++) acc += bf2f(zv[j]) * bf2f(wv[j]);
    }
    acc += __shfl_down(acc, 4, 64);
    acc += __shfl_down(acc, 2, 64);
    acc += __shfl_down(acc, 1, 64);
    if (t8 == 0) z1[out] = gelu_exact(acc + b1[d]);
}

// ---------------------------------------------------------------------------
// Head stage 4: out[b,o] = z1[b] @ w2[:,o] + b2[o]. 1 block, 256 threads.
// ---------------------------------------------------------------------------
__global__ __launch_bounds__(256) void head_final_kernel(
    const float* __restrict__ z1, const float* __restrict__ w2,
    const float* __restrict__ b2, float* __restrict__ out)
{
    int tid = threadIdx.x;
    int g = tid >> 3, t8 = tid & 7;
    if (g < 24) {
        int b = g / 3, o = g % 3;
        float acc = 0.f;
        for (int k = t8; k < 512; k += 8)
            acc += z1[b * 512 + k] * w2[k * 3 + o];
        acc += __shfl_down(acc, 4, 64);
        acc += __shfl_down(acc, 2, 64);
        acc += __shfl_down(acc, 1, 64);
        if (t8 == 0) out[b * 3 + o] = acc + b2[o];
    }
}

// ---------------------------------------------------------------------------
extern "C" void kernel_launch(void* const* d_in, const int* in_sizes, int n_in,
                              void* d_out, int out_size, void* d_ws, size_t ws_size,
                              hipStream_t stream) {
    const float* x       = (const float*)d_in[0];
    const float* proj_w  = (const float*)d_in[2];
    const float* proj_b  = (const float*)d_in[3];
    const float* pos_emb = (const float*)d_in[4];
    const float* tok_emb = (const float*)d_in[5];
    const float* eln_s   = (const float*)d_in[6];
    const float* eln_b   = (const float*)d_in[7];
    const float* wq      = (const float*)d_in[8];
    const float* bq      = (const float*)d_in[9];
    const float* wk      = (const float*)d_in[10];
    const float* bk      = (const float*)d_in[11];
    const float* wv      = (const float*)d_in[12];
    const float* bv      = (const float*)d_in[13];
    const float* wo      = (const float*)d_in[14];
    const float* bo      = (const float*)d_in[15];
    const float* ln1_s   = (const float*)d_in[16];
    const float* ln1_b   = (const float*)d_in[17];
    const float* wi      = (const float*)d_in[18];
    const float* bi      = (const float*)d_in[19];
    const float* wo2     = (const float*)d_in[20];
    const float* bo2     = (const float*)d_in[21];
    const float* ln2_s   = (const float*)d_in[22];
    const float* ln2_b   = (const float*)d_in[23];
    const float* pool_w  = (const float*)d_in[24];
    const float* pool_b  = (const float*)d_in[25];
    const float* hln_s   = (const float*)d_in[26];
    const float* hln_b   = (const float*)d_in[27];
    const float* hw1     = (const float*)d_in[28];
    const float* hb1     = (const float*)d_in[29];
    const float* hw2     = (const float*)d_in[30];
    const float* hb2     = (const float*)d_in[31];

    char* wp = (char*)d_ws;
    auto alloc = [&](size_t bytes) {
        char* p = wp; wp += (bytes + 255) & ~(size_t)255; return p;
    };
    float*          h       = (float*)alloc(8192ll * 768 * 4);
    __hip_bfloat16* qkv_bf  = (__hip_bfloat16*)alloc(8192ll * 2304 * 2);
    __hip_bfloat16* t_bf    = (__hip_bfloat16*)alloc(8192ll * 768 * 2);
    __hip_bfloat16* mlp_bf  = (__hip_bfloat16*)alloc(8192ll * 3072 * 2);
    __hip_bfloat16* h_bf    = (__hip_bfloat16*)alloc(8192ll * 768 * 2);
    __hip_bfloat16* a_bf    = (__hip_bfloat16*)alloc(8192ll * 768 * 2);
    __hip_bfloat16* qkvw_t  = (__hip_bfloat16*)alloc(3ll * 2304 * 768 * 2);
    __hip_bfloat16* wo_t    = (__hip_bfloat16*)alloc(3ll * 768 * 768 * 2);
    __hip_bfloat16* wi_t    = (__hip_bfloat16*)alloc(3ll * 3072 * 768 * 2);
    __hip_bfloat16* wo2_t   = (__hip_bfloat16*)alloc(3ll * 768 * 3072 * 2);
    float*          qkv_b   = (float*)alloc(3ll * 2304 * 4);
    __hip_bfloat16* xr_bf   = (__hip_bfloat16*)alloc(8192ll * 192 * 2);
    __hip_bfloat16* projw_t = (__hip_bfloat16*)alloc(768ll * 192 * 2);
    __hip_bfloat16* poolw_t = (__hip_bfloat16*)alloc(768ll * 768 * 2);
    __hip_bfloat16* w1_t    = (__hip_bfloat16*)alloc(512ll * 768 * 2);
    float*          pooled  = (float*)alloc(8ll * 768 * 4);
    __hip_bfloat16* z_bf    = (__hip_bfloat16*)alloc(8ll * 768 * 2);
    float*          z1      = (float*)alloc(8ll * 512 * 4);

    // ---- weight conversion (every call; graph-safe) ----
    transpose_bf16<<<dim3(24, 24, 3), 256, 0, stream>>>(wq, qkvw_t,               768, 768,  768ll * 768,  2304ll * 768);
    transpose_bf16<<<dim3(24, 24, 3), 256, 0, stream>>>(wk, qkvw_t + 768 * 768,   768, 768,  768ll * 768,  2304ll * 768);
    transpose_bf16<<<dim3(24, 24, 3), 256, 0, stream>>>(wv, qkvw_t + 1536 * 768,  768, 768,  768ll * 768,  2304ll * 768);
    transpose_bf16<<<dim3(24, 24, 3), 256, 0, stream>>>(wo, wo_t,                 768, 768,  768ll * 768,  768ll * 768);
    transpose_bf16<<<dim3(96, 24, 3), 256, 0, stream>>>(wi, wi_t,                 768, 3072, 768ll * 3072, 3072ll * 768);
    transpose_bf16<<<dim3(24, 96, 3), 256, 0, stream>>>(wo2, wo2_t,               3072, 768, 3072ll * 768, 768ll * 3072);
    transpose_bf16<<<dim3(24, 6, 1),  256, 0, stream>>>(proj_w, projw_t,          192, 768,  0, 0);
    transpose_bf16<<<dim3(24, 24, 1), 256, 0, stream>>>(pool_w, poolw_t,          768, 768,  0, 0);
    transpose_bf16<<<dim3(16, 24, 1), 256, 0, stream>>>(hw1, w1_t,                768, 512,  0, 0);
    pack_qkv_bias<<<3, 768, 0, stream>>>(bq, bk, bv, qkv_b);

    // ---- embed as MFMA GEMM ----
    gather_x<<<8192, 192, 0, stream>>>(x, xr_bf);
    mfma_gemm<0><<<6 * 64, 256, 0, stream>>>(
        xr_bf, projw_t, proj_b, t_bf, 8192, 768, 192);
    pos_ln_kernel<<<8192, 192, 0, stream>>>(t_bf, pos_emb, tok_emb, eln_s, eln_b, h, h_bf);

    for (int l = 0; l < 3; l++) {
        mfma_gemm<0><<<18 * 64, 256, 0, stream>>>(
            h_bf, qkvw_t + (long)l * 2304 * 768, qkv_b + l * 2304, qkv_bf,
            8192, 2304, 768);
        attn_kernel<<<768, 256, 0, stream>>>(qkv_bf, a_bf);
        mfma_gemm<0><<<6 * 64, 256, 0, stream>>>(
            a_bf, wo_t + (long)l * 768 * 768, bo + l * 768, t_bf,
            8192, 768, 768);
        add_ln_kernel<<<8192, 192, 0, stream>>>(h, t_bf, ln1_s + l * 768, ln1_b + l * 768, h_bf);
        mfma_gemm<1><<<24 * 64, 256, 0, stream>>>(
            h_bf, wi_t + (long)l * 3072 * 768, bi + l * 3072, mlp_bf,
            8192, 3072, 768);
        mfma_gemm<0><<<6 * 64, 256, 0, stream>>>(
            mlp_bf, wo2_t + (long)l * 768 * 3072, bo2 + l * 768, t_bf,
            8192, 768, 3072);
        add_ln_kernel<<<8192, 192, 0, stream>>>(h, t_bf, ln2_s + l * 768, ln2_b + l * 768, h_bf);
    }

    // ---- head: pool -> LN -> MLP -> final ----
    pool_split<<<192, 256, 0, stream>>>(h_bf, poolw_t, pool_b, pooled);
    ln_z_kernel<<<8, 256, 0, stream>>>(pooled, hln_s, hln_b, z_bf);
    mlp_split<<<128, 256, 0, stream>>>(z_bf, w1_t, hb1, z1);
    head_final_kernel<<<1, 256, 0, stream>>>(z1, hw2, hb2, (float*)d_out);
}